// Round 4
// baseline (822.559 us; speedup 1.0000x reference)
//
#include <hip/hip_runtime.h>
#include <math.h>

#define H 8
#define FD 128
#define SCALE 0.25f

typedef __attribute__((ext_vector_type(8))) short bf16x8;
typedef __attribute__((ext_vector_type(4))) float f32x4;

__device__ __forceinline__ unsigned short bf_rne(float f) {
    unsigned u = __float_as_uint(f);
    u += 0x7FFFu + ((u >> 16) & 1u);
    return (unsigned short)(u >> 16);
}
__device__ __forceinline__ float bf_to_f(unsigned short s) {
    return __uint_as_float(((unsigned)s) << 16);
}
__device__ __forceinline__ bf16x8 cvt8(const float* __restrict__ p) {
    float4 a = *(const float4*)p;
    float4 b = *(const float4*)(p + 4);
    bf16x8 r;
    r[0] = bf_rne(a.x); r[1] = bf_rne(a.y); r[2] = bf_rne(a.z); r[3] = bf_rne(a.w);
    r[4] = bf_rne(b.x); r[5] = bf_rne(b.y); r[6] = bf_rne(b.z); r[7] = bf_rne(b.w);
    return r;
}

// ---- one-time weight conversion fp32 -> bf16 (4 x 128x128) ----
__global__ __launch_bounds__(256) void prep_kernel(
    const float* __restrict__ Wq, const float* __restrict__ Wk,
    const float* __restrict__ Wv, const float* __restrict__ Wo,
    unsigned short* __restrict__ oq, unsigned short* __restrict__ ok,
    unsigned short* __restrict__ ov, unsigned short* __restrict__ oo) {
    int i = blockIdx.x * 256 + threadIdx.x;  // 0..4095 float4 groups
    const float* src[4] = {Wq, Wk, Wv, Wo};
    unsigned short* dstp[4] = {oq, ok, ov, oo};
#pragma unroll
    for (int m = 0; m < 4; ++m) {
        float4 w = ((const float4*)src[m])[i];
        ushort4 p = make_ushort4(bf_rne(w.x), bf_rne(w.y), bf_rne(w.z), bf_rne(w.w));
        *(ushort4*)(dstp[m] + i * 4) = p;
    }
}

// ---- fused q (bf16 out) + v (fp32 out) projection, MFMA, 64-row tile ----
__global__ __launch_bounds__(256) void qv_kernel(
    const float* __restrict__ X, const unsigned short* __restrict__ Wqb,
    const unsigned short* __restrict__ Wvb, const float* __restrict__ bq,
    const float* __restrict__ bv, unsigned short* __restrict__ qb,
    float* __restrict__ v, int Nrows) {
    const int t = threadIdx.x;
    const int lane = t & 63, wid = t >> 6;
    const int lm = lane & 15, lq = lane >> 4;
    const int r0 = blockIdx.x * 64 + wid * 16;

    bf16x8 a[4];
#pragma unroll
    for (int s = 0; s < 4; ++s) {
        int r = r0 + lm;
        if (r >= Nrows) r = Nrows - 1;
        a[s] = cvt8(X + (size_t)r * FD + s * 32 + lq * 8);
    }
#pragma unroll
    for (int g = 0; g < 2; ++g) {
        const unsigned short* Wb = g ? Wvb : Wqb;
        const float* bias = g ? bv : bq;
        f32x4 acc[8];
#pragma unroll
        for (int nt = 0; nt < 8; ++nt) {
            float b = bias[nt * 16 + lm];
            acc[nt][0] = b; acc[nt][1] = b; acc[nt][2] = b; acc[nt][3] = b;
        }
#pragma unroll
        for (int s = 0; s < 4; ++s)
#pragma unroll
            for (int nt = 0; nt < 8; ++nt) {
                bf16x8 bf = *(const bf16x8*)(Wb + (nt * 16 + lm) * FD + s * 32 + lq * 8);
                acc[nt] = __builtin_amdgcn_mfma_f32_16x16x32_bf16(
                    a[s], bf, acc[nt], 0, 0, 0);
            }
#pragma unroll
        for (int nt = 0; nt < 8; ++nt)
#pragma unroll
            for (int r = 0; r < 4; ++r) {
                int row = r0 + lq * 4 + r;
                if (row >= Nrows) continue;
                int col = nt * 16 + lm;
                if (g == 0)
                    qb[(size_t)row * FD + col] = bf_rne(acc[nt][r]);
                else
                    v[(size_t)row * FD + col] = acc[nt][r];
            }
    }
}

// ================== counting sort by dst ==================
__global__ __launch_bounds__(256) void hist_kernel(
    const int* __restrict__ dst, int* __restrict__ cnt, int E) {
    int i = blockIdx.x * 256 + threadIdx.x;
    if (i < E) atomicAdd(cnt + dst[i], 1);
}

// block-wise exclusive scan (Hillis-Steele in LDS), block totals -> bsum
__global__ __launch_bounds__(256) void scan1_kernel(
    const int* __restrict__ cnt, int* __restrict__ offs,
    int* __restrict__ bsum, int N) {
    __shared__ int sd[256];
    int t = threadIdx.x, i = blockIdx.x * 256 + t;
    int x = (i < N) ? cnt[i] : 0;
    int v = x;
    sd[t] = v; __syncthreads();
#pragma unroll
    for (int off = 1; off < 256; off <<= 1) {
        int y = (t >= off) ? sd[t - off] : 0;
        __syncthreads();
        v += y; sd[t] = v; __syncthreads();
    }
    if (i < N) offs[i] = v - x;       // exclusive within block
    if (t == 255) bsum[blockIdx.x] = v;
}

// exclusive scan of block totals (NB <= 256), in place
__global__ __launch_bounds__(256) void scan2_kernel(int* __restrict__ bsum, int NB) {
    __shared__ int sd[256];
    int t = threadIdx.x;
    int x = (t < NB) ? bsum[t] : 0;
    int v = x;
    sd[t] = v; __syncthreads();
#pragma unroll
    for (int off = 1; off < 256; off <<= 1) {
        int y = (t >= off) ? sd[t - off] : 0;
        __syncthreads();
        v += y; sd[t] = v; __syncthreads();
    }
    if (t < NB) bsum[t] = v - x;
}

// add block offsets; copy to cursor; offs[N] = E
__global__ __launch_bounds__(256) void scan3_kernel(
    int* __restrict__ offs, int* __restrict__ cursor,
    const int* __restrict__ bsum, int N, int E) {
    int i = blockIdx.x * 256 + threadIdx.x;
    if (i < N) {
        int o = offs[i] + bsum[blockIdx.x];
        offs[i] = o;
        cursor[i] = o;
    }
    if (i == 0) offs[N] = E;
}

// rank each edge within its dst segment; permute src and att into sorted order
__global__ __launch_bounds__(256) void scatter_kernel(
    const int* __restrict__ src, const int* __restrict__ dst,
    const float* __restrict__ distance, const float* __restrict__ lam,
    int* __restrict__ cursor, int* __restrict__ rank,
    int* __restrict__ srcs_s, float* __restrict__ att_s, int E) {
    int i = blockIdx.x * 256 + threadIdx.x;
    if (i >= E) return;
    int d = dst[i];
    int r = atomicAdd(cursor + d, 1);
    rank[i] = r;
    srcs_s[r] = src[i];
    att_s[r] = __expf(lam[0] * __logf(distance[i]));
}

// ---- k projection GEMM, output scattered into dst-sorted order ----
__global__ __launch_bounds__(256) void kproj_sorted_kernel(
    const float* __restrict__ X, const unsigned short* __restrict__ Wkb,
    const float* __restrict__ bk, const int* __restrict__ rank,
    unsigned short* __restrict__ kb, int E) {
    const int t = threadIdx.x;
    const int lane = t & 63, wid = t >> 6;
    const int lm = lane & 15, lq = lane >> 4;
    const int r0 = blockIdx.x * 64 + wid * 16;

    bf16x8 a[4];
#pragma unroll
    for (int s = 0; s < 4; ++s) {
        int r = r0 + lm;
        if (r >= E) r = E - 1;
        a[s] = cvt8(X + (size_t)r * FD + s * 32 + lq * 8);
    }
    f32x4 acc[8];
#pragma unroll
    for (int nt = 0; nt < 8; ++nt) {
        float b = bk[nt * 16 + lm];
        acc[nt][0] = b; acc[nt][1] = b; acc[nt][2] = b; acc[nt][3] = b;
    }
#pragma unroll
    for (int s = 0; s < 4; ++s)
#pragma unroll
        for (int nt = 0; nt < 8; ++nt) {
            bf16x8 bf = *(const bf16x8*)(Wkb + (nt * 16 + lm) * FD + s * 32 + lq * 8);
            acc[nt] = __builtin_amdgcn_mfma_f32_16x16x32_bf16(
                a[s], bf, acc[nt], 0, 0, 0);
        }
#pragma unroll
    for (int r = 0; r < 4; ++r) {
        int e = r0 + lq * 4 + r;
        if (e >= E) continue;
        int rk = rank[e];
        unsigned short* dstrow = kb + (size_t)rk * FD + lm;
#pragma unroll
        for (int nt = 0; nt < 8; ++nt)
            dstrow[nt * 16] = bf_rne(acc[nt][r]);
    }
}

// ---- segmented attention: one thread per (node, head), zero atomics ----
// kb/srcs_s/att_s are dst-sorted; segment of node n = [offs[n], offs[n+1]).
// Folds the combine step: writes ssum directly.
__global__ __launch_bounds__(256) void seg_attn_kernel(
    const unsigned short* __restrict__ kb, const unsigned short* __restrict__ qb,
    const int* __restrict__ offs, const int* __restrict__ srcs_s,
    const float* __restrict__ att_s, float* __restrict__ ssum, int NH) {
    int i = blockIdx.x * 256 + threadIdx.x;
    if (i >= NH) return;
    int n = i >> 3, h = i & 7;
    int s0 = offs[n], s1 = offs[n + 1];

    const unsigned short* qdp = qb + (size_t)n * FD + h * 16;
    bf16x8 qd0 = *(const bf16x8*)qdp;
    bf16x8 qd1 = *(const bf16x8*)(qdp + 8);

    float den1 = 0.f, den2 = 0.f, den3 = 0.f;
    float a1 = 0.f, a2 = 0.f, a3 = 0.f;
    for (int j = s0; j < s1; ++j) {
        const unsigned short* kp = kb + (size_t)j * FD + h * 16;
        bf16x8 k0 = *(const bf16x8*)kp;
        bf16x8 k1 = *(const bf16x8*)(kp + 8);
        int s = srcs_s[j];
        const unsigned short* qsp = qb + (size_t)s * FD + h * 16;
        bf16x8 qs0 = *(const bf16x8*)qsp;
        bf16x8 qs1 = *(const bf16x8*)(qsp + 8);
        float att = att_s[j];
        float pin = 0.f, pot = 0.f, pdg = 0.f;
#pragma unroll
        for (int q = 0; q < 8; ++q) {
            float qsf = bf_to_f((unsigned short)qs0[q]);
            float qdf = bf_to_f((unsigned short)qd0[q]);
            float kf  = bf_to_f((unsigned short)k0[q]);
            pin += qsf * kf; pot += qdf * kf; pdg += qsf * qdf;
        }
#pragma unroll
        for (int q = 0; q < 8; ++q) {
            float qsf = bf_to_f((unsigned short)qs1[q]);
            float qdf = bf_to_f((unsigned short)qd1[q]);
            float kf  = bf_to_f((unsigned short)k1[q]);
            pin += qsf * kf; pot += qdf * kf; pdg += qsf * qdf;
        }
        float e1 = __expf(pin * SCALE);
        float e2 = __expf(pot * SCALE);
        float e3 = __expf(pdg * SCALE);
        den1 += e1; a1 += e1 * att;
        den2 += e2; a2 += e2 * att;
        den3 += e3; a3 += e3 * att;
    }
    float r = 0.f;
    if (den1 != 0.f) r += a1 / den1;
    if (den2 != 0.f) r += a2 / den2;
    if (den3 != 0.f) r += a3 / den3;
    ssum[i] = r;
}

// ================== fallback path (proven round-3) ==================
__global__ __launch_bounds__(256) void edge_kernel(
    const float* __restrict__ eh, const unsigned short* __restrict__ Wkb,
    const float* __restrict__ bk, const unsigned short* __restrict__ qb,
    const int* __restrict__ src, const int* __restrict__ dst,
    const float* __restrict__ distance, const float* __restrict__ lam,
    float* __restrict__ den1, float* __restrict__ den2,
    float* __restrict__ den3, float* __restrict__ sc1,
    float* __restrict__ sc2, float* __restrict__ sc3, int E) {
    __shared__ unsigned short lK[64 * 128];
    const int t = threadIdx.x;
    const int e0 = blockIdx.x * 64;
    const int lane = t & 63, wid = t >> 6;
    const int lm = lane & 15, lq = lane >> 4;
    const int wm = wid * 16;

    bf16x8 a[4];
#pragma unroll
    for (int s = 0; s < 4; ++s) {
        int e = e0 + wm + lm;
        if (e >= E) e = E - 1;
        a[s] = cvt8(eh + (size_t)e * FD + s * 32 + lq * 8);
    }
    f32x4 acc[8];
#pragma unroll
    for (int nt = 0; nt < 8; ++nt) {
        float b = bk[nt * 16 + lm];
        acc[nt][0] = b; acc[nt][1] = b; acc[nt][2] = b; acc[nt][3] = b;
    }
#pragma unroll
    for (int s = 0; s < 4; ++s)
#pragma unroll
        for (int nt = 0; nt < 8; ++nt) {
            bf16x8 bf = *(const bf16x8*)(Wkb + (nt * 16 + lm) * FD + s * 32 + lq * 8);
            acc[nt] = __builtin_amdgcn_mfma_f32_16x16x32_bf16(
                a[s], bf, acc[nt], 0, 0, 0);
        }
#pragma unroll
    for (int nt = 0; nt < 8; ++nt)
#pragma unroll
        for (int r = 0; r < 4; ++r) {
            int m = wm + lq * 4 + r;
            int n = nt * 16 + lm;
            int swb = (n >> 3) ^ (m & 7);
            lK[m * 128 + swb * 8 + (n & 7)] = bf_rne(acc[nt][r]);
        }
    __syncthreads();

    const float lamv = lam[0];
#pragma unroll
    for (int i = 0; i < 2; ++i) {
        int p = i * 256 + t;
        int el = p >> 3, h = p & 7;
        int e = e0 + el;
        if (e >= E) continue;
        int si = src[e], di = dst[e];
        const unsigned short* qsp = qb + (size_t)si * FD + h * 16;
        const unsigned short* qdp = qb + (size_t)di * FD + h * 16;
        bf16x8 qs0 = *(const bf16x8*)qsp;
        bf16x8 qs1 = *(const bf16x8*)(qsp + 8);
        bf16x8 qd0 = *(const bf16x8*)qdp;
        bf16x8 qd1 = *(const bf16x8*)(qdp + 8);
        int swb0 = (2 * h) ^ (el & 7), swb1 = (2 * h + 1) ^ (el & 7);
        bf16x8 k0 = *(const bf16x8*)(lK + el * 128 + swb0 * 8);
        bf16x8 k1 = *(const bf16x8*)(lK + el * 128 + swb1 * 8);
        float pin = 0.f, pot = 0.f, pdg = 0.f;
#pragma unroll
        for (int j = 0; j < 8; ++j) {
            float qsf = bf_to_f((unsigned short)qs0[j]);
            float qdf = bf_to_f((unsigned short)qd0[j]);
            float kf = bf_to_f((unsigned short)k0[j]);
            pin += qsf * kf; pot += qdf * kf; pdg += qsf * qdf;
        }
#pragma unroll
        for (int j = 0; j < 8; ++j) {
            float qsf = bf_to_f((unsigned short)qs1[j]);
            float qdf = bf_to_f((unsigned short)qd1[j]);
            float kf = bf_to_f((unsigned short)k1[j]);
            pin += qsf * kf; pot += qdf * kf; pdg += qsf * qdf;
        }
        float att = __expf(lamv * __logf(distance[e]));
        float e1 = __expf(pin * SCALE);
        float e2 = __expf(pot * SCALE);
        float e3 = __expf(pdg * SCALE);
        int nb = di * H + h;
        atomicAdd(den1 + nb, e1); atomicAdd(sc1 + nb, e1 * att);
        atomicAdd(den2 + nb, e2); atomicAdd(sc2 + nb, e2 * att);
        atomicAdd(den3 + nb, e3); atomicAdd(sc3 + nb, e3 * att);
    }
}

__global__ __launch_bounds__(256) void combine_kernel(
    const float* __restrict__ den1, const float* __restrict__ den2,
    const float* __restrict__ den3, const float* __restrict__ sc1,
    const float* __restrict__ sc2, const float* __restrict__ sc3,
    float* __restrict__ ssum, int NH) {
    int i = blockIdx.x * 256 + threadIdx.x;
    if (i >= NH) return;
    float r = 0.f;
    float d1 = den1[i]; if (d1 != 0.f) r += sc1[i] / d1;
    float d2 = den2[i]; if (d2 != 0.f) r += sc2[i] / d2;
    float d3 = den3[i]; if (d3 != 0.f) r += sc3[i] / d3;
    ssum[i] = r;
}

// ---- out = leaky_relu( (ssum*v) @ Wo.T + bo ), MFMA, 64-row tile ----
__global__ __launch_bounds__(256) void out_kernel(
    const float* __restrict__ v, const float* __restrict__ ssum,
    const unsigned short* __restrict__ Wob, const float* __restrict__ bo,
    float* __restrict__ out, int Nrows) {
    const int t = threadIdx.x;
    const int lane = t & 63, wid = t >> 6;
    const int lm = lane & 15, lq = lane >> 4;
    const int r0 = blockIdx.x * 64 + wid * 16;

    bf16x8 a[4];
#pragma unroll
    for (int s = 0; s < 4; ++s) {
        int r = r0 + lm;
        if (r >= Nrows) r = Nrows - 1;
        int k0 = s * 32 + lq * 8;
        float sc = ssum[r * H + (k0 >> 4)];  // [N][H]
        const float* p = v + (size_t)r * FD + k0;
        float4 x = *(const float4*)p;
        float4 y = *(const float4*)(p + 4);
        bf16x8 f;
        f[0] = bf_rne(x.x * sc); f[1] = bf_rne(x.y * sc);
        f[2] = bf_rne(x.z * sc); f[3] = bf_rne(x.w * sc);
        f[4] = bf_rne(y.x * sc); f[5] = bf_rne(y.y * sc);
        f[6] = bf_rne(y.z * sc); f[7] = bf_rne(y.w * sc);
        a[s] = f;
    }
    f32x4 acc[8];
#pragma unroll
    for (int nt = 0; nt < 8; ++nt) {
        float b = bo[nt * 16 + lm];
        acc[nt][0] = b; acc[nt][1] = b; acc[nt][2] = b; acc[nt][3] = b;
    }
#pragma unroll
    for (int s = 0; s < 4; ++s)
#pragma unroll
        for (int nt = 0; nt < 8; ++nt) {
            bf16x8 bf = *(const bf16x8*)(Wob + (nt * 16 + lm) * FD + s * 32 + lq * 8);
            acc[nt] = __builtin_amdgcn_mfma_f32_16x16x32_bf16(
                a[s], bf, acc[nt], 0, 0, 0);
        }
#pragma unroll
    for (int nt = 0; nt < 8; ++nt)
#pragma unroll
        for (int r = 0; r < 4; ++r) {
            int row = r0 + lq * 4 + r;
            if (row >= Nrows) continue;
            int col = nt * 16 + lm;
            float x = acc[nt][r];
            out[(size_t)row * FD + col] = x > 0.f ? x : 0.1f * x;
        }
}

extern "C" void kernel_launch(void* const* d_in, const int* in_sizes, int n_in,
                              void* d_out, int out_size, void* d_ws,
                              size_t ws_size, hipStream_t stream) {
    (void)n_in; (void)out_size;
    const float* node_h   = (const float*)d_in[0];
    const float* edge_h   = (const float*)d_in[1];
    const float* distance = (const float*)d_in[2];
    const float* Wq = (const float*)d_in[3];
    const float* bq = (const float*)d_in[4];
    const float* Wk = (const float*)d_in[5];
    const float* bk = (const float*)d_in[6];
    const float* Wv = (const float*)d_in[7];
    const float* bv = (const float*)d_in[8];
    const float* Wo = (const float*)d_in[9];
    const float* bo = (const float*)d_in[10];
    const float* lam = (const float*)d_in[11];
    const int* src = (const int*)d_in[12];
    const int* dst = (const int*)d_in[13];

    int N = in_sizes[0] / FD;
    int E = in_sizes[1] / FD;
    int NH = N * H;
    int NB = (N + 255) / 256;

    // ---- workspace layout (256B-aligned bumps) ----
    char* p = (char*)d_ws;
    auto alloc = [&](size_t bytes) -> char* {
        char* r = p;
        p += (bytes + 255) & ~(size_t)255;
        return r;
    };
    unsigned short* Wqb = (unsigned short*)alloc(FD * FD * 2);
    unsigned short* Wkb = (unsigned short*)alloc(FD * FD * 2);
    unsigned short* Wvb = (unsigned short*)alloc(FD * FD * 2);
    unsigned short* Wob = (unsigned short*)alloc(FD * FD * 2);
    unsigned short* qb  = (unsigned short*)alloc((size_t)N * FD * 2);
    float* v    = (float*)alloc((size_t)N * FD * 4);
    float* ssum = (float*)alloc((size_t)NH * 4);
    char* branch_base = p;

    // main-path extras
    int* cnt    = (int*)alloc((size_t)N * 4);
    int* offs   = (int*)alloc((size_t)(N + 1) * 4);
    int* cursor = (int*)alloc((size_t)N * 4);
    int* bsum   = (int*)alloc((size_t)NB * 4);
    int* rank   = (int*)alloc((size_t)E * 4);
    int* srcs_s = (int*)alloc((size_t)E * 4);
    float* att_s = (float*)alloc((size_t)E * 4);
    unsigned short* kb = (unsigned short*)alloc((size_t)E * FD * 2);
    size_t need_main = (size_t)(p - (char*)d_ws);

    bool main_ok = (ws_size >= need_main) && (NB <= 256);

    prep_kernel<<<16, 256, 0, stream>>>(Wq, Wk, Wv, Wo, Wqb, Wkb, Wvb, Wob);

    int nb = (N + 63) / 64;
    qv_kernel<<<nb, 256, 0, stream>>>(node_h, Wqb, Wvb, bq, bv, qb, v, N);

    if (main_ok) {
        // ---- sort-based, atomic-free main path ----
        hipMemsetAsync(cnt, 0, (size_t)N * 4, stream);
        int eb = (E + 255) / 256;
        hist_kernel<<<eb, 256, 0, stream>>>(dst, cnt, E);
        scan1_kernel<<<NB, 256, 0, stream>>>(cnt, offs, bsum, N);
        scan2_kernel<<<1, 256, 0, stream>>>(bsum, NB);
        scan3_kernel<<<NB, 256, 0, stream>>>(offs, cursor, bsum, N, E);
        scatter_kernel<<<eb, 256, 0, stream>>>(src, dst, distance, lam,
                                               cursor, rank, srcs_s, att_s, E);
        kproj_sorted_kernel<<<(E + 63) / 64, 256, 0, stream>>>(
            edge_h, Wkb, bk, rank, kb, E);
        seg_attn_kernel<<<(NH + 255) / 256, 256, 0, stream>>>(
            kb, qb, offs, srcs_s, att_s, ssum, NH);
    } else {
        // ---- fallback: proven round-3 fused atomic path ----
        char* q = branch_base;
        auto alloc2 = [&](size_t bytes) -> char* {
            char* r = q;
            q += (bytes + 255) & ~(size_t)255;
            return r;
        };
        float* den1 = (float*)alloc2((size_t)NH * 4);
        float* den2 = (float*)alloc2((size_t)NH * 4);
        float* den3 = (float*)alloc2((size_t)NH * 4);
        float* sc1  = (float*)alloc2((size_t)NH * 4);
        float* sc2  = (float*)alloc2((size_t)NH * 4);
        float* sc3  = (float*)alloc2((size_t)NH * 4);
        hipMemsetAsync(den1, 0, (size_t)(q - (char*)den1), stream);
        int ebl = (E + 63) / 64;
        edge_kernel<<<ebl, 256, 0, stream>>>(edge_h, Wkb, bk, qb, src, dst,
                                             distance, lam,
                                             den1, den2, den3, sc1, sc2, sc3, E);
        combine_kernel<<<(NH + 255) / 256, 256, 0, stream>>>(
            den1, den2, den3, sc1, sc2, sc3, ssum, NH);
    }

    out_kernel<<<nb, 256, 0, stream>>>(v, ssum, Wob, bo, (float*)d_out, N);
}

// Round 5
// 808.000 us; speedup vs baseline: 1.0180x; 1.0180x over previous
//
#include <hip/hip_runtime.h>
#include <math.h>

#define H 8
#define FD 128
#define SCALE 0.25f

typedef __attribute__((ext_vector_type(8))) short bf16x8;
typedef __attribute__((ext_vector_type(4))) float f32x4;

__device__ __forceinline__ unsigned short bf_rne(float f) {
    unsigned u = __float_as_uint(f);
    u += 0x7FFFu + ((u >> 16) & 1u);
    return (unsigned short)(u >> 16);
}
__device__ __forceinline__ float bf_to_f(unsigned short s) {
    return __uint_as_float(((unsigned)s) << 16);
}
__device__ __forceinline__ bf16x8 cvt8(const float* __restrict__ p) {
    float4 a = *(const float4*)p;
    float4 b = *(const float4*)(p + 4);
    bf16x8 r;
    r[0] = bf_rne(a.x); r[1] = bf_rne(a.y); r[2] = bf_rne(a.z); r[3] = bf_rne(a.w);
    r[4] = bf_rne(b.x); r[5] = bf_rne(b.y); r[6] = bf_rne(b.z); r[7] = bf_rne(b.w);
    return r;
}

// ---- one-time weight conversion fp32 -> bf16 (4 x 128x128) ----
__global__ __launch_bounds__(256) void prep_kernel(
    const float* __restrict__ Wq, const float* __restrict__ Wk,
    const float* __restrict__ Wv, const float* __restrict__ Wo,
    unsigned short* __restrict__ oq, unsigned short* __restrict__ ok,
    unsigned short* __restrict__ ov, unsigned short* __restrict__ oo) {
    int i = blockIdx.x * 256 + threadIdx.x;  // 0..4095 float4 groups
    const float* src[4] = {Wq, Wk, Wv, Wo};
    unsigned short* dstp[4] = {oq, ok, ov, oo};
#pragma unroll
    for (int m = 0; m < 4; ++m) {
        float4 w = ((const float4*)src[m])[i];
        ushort4 p = make_ushort4(bf_rne(w.x), bf_rne(w.y), bf_rne(w.z), bf_rne(w.w));
        *(ushort4*)(dstp[m] + i * 4) = p;
    }
}

// ---- fused q (bf16) + v (fp32) projection, MFMA with SWAPPED operands:
// mfma(W_frag, X_frag) = (X @ W^T)^T fragment-wise, so each lane owns one
// output row (r0+lm) and 4 CONSECUTIVE cols per acc group -> vector stores.
__global__ __launch_bounds__(256) void qv_kernel(
    const float* __restrict__ X, const unsigned short* __restrict__ Wqb,
    const unsigned short* __restrict__ Wvb, const float* __restrict__ bq,
    const float* __restrict__ bv, unsigned short* __restrict__ qb,
    float* __restrict__ v, int Nrows) {
    const int t = threadIdx.x;
    const int lane = t & 63, wid = t >> 6;
    const int lm = lane & 15, lq = lane >> 4;
    const int r0 = blockIdx.x * 64 + wid * 16;
    const int er = r0 + lm;                 // this lane's output row
    const int erc = er < Nrows ? er : Nrows - 1;

    bf16x8 x[4];
#pragma unroll
    for (int s = 0; s < 4; ++s)
        x[s] = cvt8(X + (size_t)erc * FD + s * 32 + lq * 8);

#pragma unroll
    for (int g = 0; g < 2; ++g) {
        const unsigned short* Wb = g ? Wvb : Wqb;
        const float* bias = g ? bv : bq;
        f32x4 acc[8];
#pragma unroll
        for (int nt = 0; nt < 8; ++nt) {
            float4 bb = *(const float4*)(bias + nt * 16 + lq * 4);
            acc[nt][0] = bb.x; acc[nt][1] = bb.y;
            acc[nt][2] = bb.z; acc[nt][3] = bb.w;
        }
#pragma unroll
        for (int s = 0; s < 4; ++s)
#pragma unroll
            for (int nt = 0; nt < 8; ++nt) {
                bf16x8 w = *(const bf16x8*)(Wb + (nt * 16 + lm) * FD + s * 32 + lq * 8);
                acc[nt] = __builtin_amdgcn_mfma_f32_16x16x32_bf16(
                    w, x[s], acc[nt], 0, 0, 0);  // swapped: D^T
            }
        if (er < Nrows) {
            if (g == 0) {
                unsigned short* dr = qb + (size_t)er * FD;
#pragma unroll
                for (int nt = 0; nt < 8; ++nt) {
                    ushort4 u = make_ushort4(bf_rne(acc[nt][0]), bf_rne(acc[nt][1]),
                                             bf_rne(acc[nt][2]), bf_rne(acc[nt][3]));
                    *(ushort4*)(dr + nt * 16 + lq * 4) = u;
                }
            } else {
                float* dr = v + (size_t)er * FD;
#pragma unroll
                for (int nt = 0; nt < 8; ++nt) {
                    float4 u = make_float4(acc[nt][0], acc[nt][1],
                                           acc[nt][2], acc[nt][3]);
                    *(float4*)(dr + nt * 16 + lq * 4) = u;
                }
            }
        }
    }
}

// ================== counting sort by dst ==================
__global__ __launch_bounds__(256) void hist_kernel(
    const int* __restrict__ dst, int* __restrict__ cnt, int E) {
    int i = blockIdx.x * 256 + threadIdx.x;
    if (i < E) atomicAdd(cnt + dst[i], 1);
}

__global__ __launch_bounds__(256) void scan1_kernel(
    const int* __restrict__ cnt, int* __restrict__ offs,
    int* __restrict__ bsum, int N) {
    __shared__ int sd[256];
    int t = threadIdx.x, i = blockIdx.x * 256 + t;
    int x = (i < N) ? cnt[i] : 0;
    int v = x;
    sd[t] = v; __syncthreads();
#pragma unroll
    for (int off = 1; off < 256; off <<= 1) {
        int y = (t >= off) ? sd[t - off] : 0;
        __syncthreads();
        v += y; sd[t] = v; __syncthreads();
    }
    if (i < N) offs[i] = v - x;       // exclusive within block
    if (t == 255) bsum[blockIdx.x] = v;
}

__global__ __launch_bounds__(256) void scan2_kernel(int* __restrict__ bsum, int NB) {
    __shared__ int sd[256];
    int t = threadIdx.x;
    int x = (t < NB) ? bsum[t] : 0;
    int v = x;
    sd[t] = v; __syncthreads();
#pragma unroll
    for (int off = 1; off < 256; off <<= 1) {
        int y = (t >= off) ? sd[t - off] : 0;
        __syncthreads();
        v += y; sd[t] = v; __syncthreads();
    }
    if (t < NB) bsum[t] = v - x;
}

__global__ __launch_bounds__(256) void scan3_kernel(
    int* __restrict__ offs, int* __restrict__ cursor,
    const int* __restrict__ bsum, int N, int E) {
    int i = blockIdx.x * 256 + threadIdx.x;
    if (i < N) {
        int o = offs[i] + bsum[blockIdx.x];
        offs[i] = o;
        cursor[i] = o;
    }
    if (i == 0) offs[N] = E;
}

// rank each edge within its dst segment; permute src and att into sorted order
__global__ __launch_bounds__(256) void scatter_kernel(
    const int* __restrict__ src, const int* __restrict__ dst,
    const float* __restrict__ distance, const float* __restrict__ lam,
    int* __restrict__ cursor, int* __restrict__ rank,
    int* __restrict__ srcs_s, float* __restrict__ att_s, int E) {
    int i = blockIdx.x * 256 + threadIdx.x;
    if (i >= E) return;
    int d = dst[i];
    int r = atomicAdd(cursor + d, 1);
    rank[i] = r;
    srcs_s[r] = src[i];
    att_s[r] = __expf(lam[0] * __logf(distance[i]));
}

// ---- k projection GEMM, swapped operands -> ushort4 stores into sorted rows
__global__ __launch_bounds__(256) void kproj_sorted_kernel(
    const float* __restrict__ X, const unsigned short* __restrict__ Wkb,
    const float* __restrict__ bk, const int* __restrict__ rank,
    unsigned short* __restrict__ kb, int E) {
    const int t = threadIdx.x;
    const int lane = t & 63, wid = t >> 6;
    const int lm = lane & 15, lq = lane >> 4;
    const int r0 = blockIdx.x * 64 + wid * 16;
    const int er = r0 + lm;
    const int erc = er < E ? er : E - 1;

    bf16x8 x[4];
#pragma unroll
    for (int s = 0; s < 4; ++s)
        x[s] = cvt8(X + (size_t)erc * FD + s * 32 + lq * 8);

    f32x4 acc[8];
#pragma unroll
    for (int nt = 0; nt < 8; ++nt) {
        float4 bb = *(const float4*)(bk + nt * 16 + lq * 4);
        acc[nt][0] = bb.x; acc[nt][1] = bb.y;
        acc[nt][2] = bb.z; acc[nt][3] = bb.w;
    }
#pragma unroll
    for (int s = 0; s < 4; ++s)
#pragma unroll
        for (int nt = 0; nt < 8; ++nt) {
            bf16x8 w = *(const bf16x8*)(Wkb + (nt * 16 + lm) * FD + s * 32 + lq * 8);
            acc[nt] = __builtin_amdgcn_mfma_f32_16x16x32_bf16(
                w, x[s], acc[nt], 0, 0, 0);  // swapped: D^T
        }
    if (er < E) {
        int rk = rank[er];
        unsigned short* dr = kb + (size_t)rk * FD;
#pragma unroll
        for (int nt = 0; nt < 8; ++nt) {
            ushort4 u = make_ushort4(bf_rne(acc[nt][0]), bf_rne(acc[nt][1]),
                                     bf_rne(acc[nt][2]), bf_rne(acc[nt][3]));
            *(ushort4*)(dr + nt * 16 + lq * 4) = u;
        }
    }
}

// ---- segmented attention: 4 lanes per (node,head), zero atomics ----
// slot-strided over the segment, __shfl_xor tree reduce, writes ssum direct.
__global__ __launch_bounds__(256) void seg_attn_kernel(
    const unsigned short* __restrict__ kb, const unsigned short* __restrict__ qb,
    const int* __restrict__ offs, const int* __restrict__ srcs_s,
    const float* __restrict__ att_s, float* __restrict__ ssum, int NH) {
    int tid = blockIdx.x * 256 + threadIdx.x;
    int g = tid >> 2, slot = tid & 3;
    if (g >= NH) return;
    int n = g >> 3, h = g & 7;
    int s0 = offs[n], s1 = offs[n + 1];

    const unsigned short* qdp = qb + (size_t)n * FD + h * 16;
    bf16x8 qd0 = *(const bf16x8*)qdp;
    bf16x8 qd1 = *(const bf16x8*)(qdp + 8);

    float den1 = 0.f, den2 = 0.f, den3 = 0.f;
    float a1 = 0.f, a2 = 0.f, a3 = 0.f;
    for (int j = s0 + slot; j < s1; j += 4) {
        const unsigned short* kp = kb + (size_t)j * FD + h * 16;
        bf16x8 k0 = *(const bf16x8*)kp;
        bf16x8 k1 = *(const bf16x8*)(kp + 8);
        int s = srcs_s[j];
        const unsigned short* qsp = qb + (size_t)s * FD + h * 16;
        bf16x8 qs0 = *(const bf16x8*)qsp;
        bf16x8 qs1 = *(const bf16x8*)(qsp + 8);
        float att = att_s[j];
        float pin = 0.f, pot = 0.f, pdg = 0.f;
#pragma unroll
        for (int q = 0; q < 8; ++q) {
            float qsf = bf_to_f((unsigned short)qs0[q]);
            float qdf = bf_to_f((unsigned short)qd0[q]);
            float kf  = bf_to_f((unsigned short)k0[q]);
            pin += qsf * kf; pot += qdf * kf; pdg += qsf * qdf;
        }
#pragma unroll
        for (int q = 0; q < 8; ++q) {
            float qsf = bf_to_f((unsigned short)qs1[q]);
            float qdf = bf_to_f((unsigned short)qd1[q]);
            float kf  = bf_to_f((unsigned short)k1[q]);
            pin += qsf * kf; pot += qdf * kf; pdg += qsf * qdf;
        }
        float e1 = __expf(pin * SCALE);
        float e2 = __expf(pot * SCALE);
        float e3 = __expf(pdg * SCALE);
        den1 += e1; a1 += e1 * att;
        den2 += e2; a2 += e2 * att;
        den3 += e3; a3 += e3 * att;
    }
    // tree-reduce the 4 slots (aligned 4-lane groups within the wave)
#pragma unroll
    for (int m = 1; m <= 2; m <<= 1) {
        den1 += __shfl_xor(den1, m); a1 += __shfl_xor(a1, m);
        den2 += __shfl_xor(den2, m); a2 += __shfl_xor(a2, m);
        den3 += __shfl_xor(den3, m); a3 += __shfl_xor(a3, m);
    }
    if (slot == 0) {
        float r = 0.f;
        if (den1 != 0.f) r += a1 / den1;
        if (den2 != 0.f) r += a2 / den2;
        if (den3 != 0.f) r += a3 / den3;
        ssum[g] = r;
    }
}

// ================== fallback path (proven round-3) ==================
__global__ __launch_bounds__(256) void edge_kernel(
    const float* __restrict__ eh, const unsigned short* __restrict__ Wkb,
    const float* __restrict__ bk, const unsigned short* __restrict__ qb,
    const int* __restrict__ src, const int* __restrict__ dst,
    const float* __restrict__ distance, const float* __restrict__ lam,
    float* __restrict__ den1, float* __restrict__ den2,
    float* __restrict__ den3, float* __restrict__ sc1,
    float* __restrict__ sc2, float* __restrict__ sc3, int E) {
    __shared__ unsigned short lK[64 * 128];
    const int t = threadIdx.x;
    const int e0 = blockIdx.x * 64;
    const int lane = t & 63, wid = t >> 6;
    const int lm = lane & 15, lq = lane >> 4;
    const int wm = wid * 16;

    bf16x8 a[4];
#pragma unroll
    for (int s = 0; s < 4; ++s) {
        int e = e0 + wm + lm;
        if (e >= E) e = E - 1;
        a[s] = cvt8(eh + (size_t)e * FD + s * 32 + lq * 8);
    }
    f32x4 acc[8];
#pragma unroll
    for (int nt = 0; nt < 8; ++nt) {
        float b = bk[nt * 16 + lm];
        acc[nt][0] = b; acc[nt][1] = b; acc[nt][2] = b; acc[nt][3] = b;
    }
#pragma unroll
    for (int s = 0; s < 4; ++s)
#pragma unroll
        for (int nt = 0; nt < 8; ++nt) {
            bf16x8 bf = *(const bf16x8*)(Wkb + (nt * 16 + lm) * FD + s * 32 + lq * 8);
            acc[nt] = __builtin_amdgcn_mfma_f32_16x16x32_bf16(
                a[s], bf, acc[nt], 0, 0, 0);
        }
#pragma unroll
    for (int nt = 0; nt < 8; ++nt)
#pragma unroll
        for (int r = 0; r < 4; ++r) {
            int m = wm + lq * 4 + r;
            int n = nt * 16 + lm;
            int swb = (n >> 3) ^ (m & 7);
            lK[m * 128 + swb * 8 + (n & 7)] = bf_rne(acc[nt][r]);
        }
    __syncthreads();

    const float lamv = lam[0];
#pragma unroll
    for (int i = 0; i < 2; ++i) {
        int p = i * 256 + t;
        int el = p >> 3, h = p & 7;
        int e = e0 + el;
        if (e >= E) continue;
        int si = src[e], di = dst[e];
        const unsigned short* qsp = qb + (size_t)si * FD + h * 16;
        const unsigned short* qdp = qb + (size_t)di * FD + h * 16;
        bf16x8 qs0 = *(const bf16x8*)qsp;
        bf16x8 qs1 = *(const bf16x8*)(qsp + 8);
        bf16x8 qd0 = *(const bf16x8*)qdp;
        bf16x8 qd1 = *(const bf16x8*)(qdp + 8);
        int swb0 = (2 * h) ^ (el & 7), swb1 = (2 * h + 1) ^ (el & 7);
        bf16x8 k0 = *(const bf16x8*)(lK + el * 128 + swb0 * 8);
        bf16x8 k1 = *(const bf16x8*)(lK + el * 128 + swb1 * 8);
        float pin = 0.f, pot = 0.f, pdg = 0.f;
#pragma unroll
        for (int j = 0; j < 8; ++j) {
            float qsf = bf_to_f((unsigned short)qs0[j]);
            float qdf = bf_to_f((unsigned short)qd0[j]);
            float kf = bf_to_f((unsigned short)k0[j]);
            pin += qsf * kf; pot += qdf * kf; pdg += qsf * qdf;
        }
#pragma unroll
        for (int j = 0; j < 8; ++j) {
            float qsf = bf_to_f((unsigned short)qs1[j]);
            float qdf = bf_to_f((unsigned short)qd1[j]);
            float kf = bf_to_f((unsigned short)k1[j]);
            pin += qsf * kf; pot += qdf * kf; pdg += qsf * qdf;
        }
        float att = __expf(lamv * __logf(distance[e]));
        float e1 = __expf(pin * SCALE);
        float e2 = __expf(pot * SCALE);
        float e3 = __expf(pdg * SCALE);
        int nb = di * H + h;
        atomicAdd(den1 + nb, e1); atomicAdd(sc1 + nb, e1 * att);
        atomicAdd(den2 + nb, e2); atomicAdd(sc2 + nb, e2 * att);
        atomicAdd(den3 + nb, e3); atomicAdd(sc3 + nb, e3 * att);
    }
}

__global__ __launch_bounds__(256) void combine_kernel(
    const float* __restrict__ den1, const float* __restrict__ den2,
    const float* __restrict__ den3, const float* __restrict__ sc1,
    const float* __restrict__ sc2, const float* __restrict__ sc3,
    float* __restrict__ ssum, int NH) {
    int i = blockIdx.x * 256 + threadIdx.x;
    if (i >= NH) return;
    float r = 0.f;
    float d1 = den1[i]; if (d1 != 0.f) r += sc1[i] / d1;
    float d2 = den2[i]; if (d2 != 0.f) r += sc2[i] / d2;
    float d3 = den3[i]; if (d3 != 0.f) r += sc3[i] / d3;
    ssum[i] = r;
}

// ---- out = leaky_relu( (ssum*v) @ Wo.T + bo ), swapped MFMA, float4 stores
__global__ __launch_bounds__(256) void out_kernel(
    const float* __restrict__ v, const float* __restrict__ ssum,
    const unsigned short* __restrict__ Wob, const float* __restrict__ bo,
    float* __restrict__ out, int Nrows) {
    const int t = threadIdx.x;
    const int lane = t & 63, wid = t >> 6;
    const int lm = lane & 15, lq = lane >> 4;
    const int r0 = blockIdx.x * 64 + wid * 16;
    const int er = r0 + lm;
    const int erc = er < Nrows ? er : Nrows - 1;

    bf16x8 x[4];
#pragma unroll
    for (int s = 0; s < 4; ++s) {
        int k0 = s * 32 + lq * 8;
        float sc = ssum[erc * H + (k0 >> 4)];  // [N][H]
        const float* p = v + (size_t)erc * FD + k0;
        float4 xa = *(const float4*)p;
        float4 ya = *(const float4*)(p + 4);
        bf16x8 f;
        f[0] = bf_rne(xa.x * sc); f[1] = bf_rne(xa.y * sc);
        f[2] = bf_rne(xa.z * sc); f[3] = bf_rne(xa.w * sc);
        f[4] = bf_rne(ya.x * sc); f[5] = bf_rne(ya.y * sc);
        f[6] = bf_rne(ya.z * sc); f[7] = bf_rne(ya.w * sc);
        x[s] = f;
    }
    f32x4 acc[8];
#pragma unroll
    for (int nt = 0; nt < 8; ++nt) {
        float4 bb = *(const float4*)(bo + nt * 16 + lq * 4);
        acc[nt][0] = bb.x; acc[nt][1] = bb.y;
        acc[nt][2] = bb.z; acc[nt][3] = bb.w;
    }
#pragma unroll
    for (int s = 0; s < 4; ++s)
#pragma unroll
        for (int nt = 0; nt < 8; ++nt) {
            bf16x8 w = *(const bf16x8*)(Wob + (nt * 16 + lm) * FD + s * 32 + lq * 8);
            acc[nt] = __builtin_amdgcn_mfma_f32_16x16x32_bf16(
                w, x[s], acc[nt], 0, 0, 0);  // swapped: D^T
        }
    if (er < Nrows) {
        float* dr = out + (size_t)er * FD;
#pragma unroll
        for (int nt = 0; nt < 8; ++nt) {
            float4 u;
            u.x = acc[nt][0] > 0.f ? acc[nt][0] : 0.1f * acc[nt][0];
            u.y = acc[nt][1] > 0.f ? acc[nt][1] : 0.1f * acc[nt][1];
            u.z = acc[nt][2] > 0.f ? acc[nt][2] : 0.1f * acc[nt][2];
            u.w = acc[nt][3] > 0.f ? acc[nt][3] : 0.1f * acc[nt][3];
            *(float4*)(dr + nt * 16 + lq * 4) = u;
        }
    }
}

extern "C" void kernel_launch(void* const* d_in, const int* in_sizes, int n_in,
                              void* d_out, int out_size, void* d_ws,
                              size_t ws_size, hipStream_t stream) {
    (void)n_in; (void)out_size;
    const float* node_h   = (const float*)d_in[0];
    const float* edge_h   = (const float*)d_in[1];
    const float* distance = (const float*)d_in[2];
    const float* Wq = (const float*)d_in[3];
    const float* bq = (const float*)d_in[4];
    const float* Wk = (const float*)d_in[5];
    const float* bk = (const float*)d_in[6];
    const float* Wv = (const float*)d_in[7];
    const float* bv = (const float*)d_in[8];
    const float* Wo = (const float*)d_in[9];
    const float* bo = (const float*)d_in[10];
    const float* lam = (const float*)d_in[11];
    const int* src = (const int*)d_in[12];
    const int* dst = (const int*)d_in[13];

    int N = in_sizes[0] / FD;
    int E = in_sizes[1] / FD;
    int NH = N * H;
    int NB = (N + 255) / 256;

    // ---- workspace layout (256B-aligned bumps) ----
    char* p = (char*)d_ws;
    auto alloc = [&](size_t bytes) -> char* {
        char* r = p;
        p += (bytes + 255) & ~(size_t)255;
        return r;
    };
    unsigned short* Wqb = (unsigned short*)alloc(FD * FD * 2);
    unsigned short* Wkb = (unsigned short*)alloc(FD * FD * 2);
    unsigned short* Wvb = (unsigned short*)alloc(FD * FD * 2);
    unsigned short* Wob = (unsigned short*)alloc(FD * FD * 2);
    unsigned short* qb  = (unsigned short*)alloc((size_t)N * FD * 2);
    float* v    = (float*)alloc((size_t)N * FD * 4);
    float* ssum = (float*)alloc((size_t)NH * 4);
    char* branch_base = p;

    // main-path extras
    int* cnt    = (int*)alloc((size_t)N * 4);
    int* offs   = (int*)alloc((size_t)(N + 1) * 4);
    int* cursor = (int*)alloc((size_t)N * 4);
    int* bsum   = (int*)alloc((size_t)NB * 4);
    int* rank   = (int*)alloc((size_t)E * 4);
    int* srcs_s = (int*)alloc((size_t)E * 4);
    float* att_s = (float*)alloc((size_t)E * 4);
    unsigned short* kb = (unsigned short*)alloc((size_t)E * FD * 2);
    size_t need_main = (size_t)(p - (char*)d_ws);

    bool main_ok = (ws_size >= need_main) && (NB <= 256);

    prep_kernel<<<16, 256, 0, stream>>>(Wq, Wk, Wv, Wo, Wqb, Wkb, Wvb, Wob);

    int nb = (N + 63) / 64;
    qv_kernel<<<nb, 256, 0, stream>>>(node_h, Wqb, Wvb, bq, bv, qb, v, N);

    if (main_ok) {
        // ---- sort-based, atomic-free main path ----
        hipMemsetAsync(cnt, 0, (size_t)N * 4, stream);
        int eb = (E + 255) / 256;
        hist_kernel<<<eb, 256, 0, stream>>>(dst, cnt, E);
        scan1_kernel<<<NB, 256, 0, stream>>>(cnt, offs, bsum, N);
        scan2_kernel<<<1, 256, 0, stream>>>(bsum, NB);
        scan3_kernel<<<NB, 256, 0, stream>>>(offs, cursor, bsum, N, E);
        scatter_kernel<<<eb, 256, 0, stream>>>(src, dst, distance, lam,
                                               cursor, rank, srcs_s, att_s, E);
        kproj_sorted_kernel<<<(E + 63) / 64, 256, 0, stream>>>(
            edge_h, Wkb, bk, rank, kb, E);
        seg_attn_kernel<<<(NH * 4 + 255) / 256, 256, 0, stream>>>(
            kb, qb, offs, srcs_s, att_s, ssum, NH);
    } else {
        // ---- fallback: proven round-3 fused atomic path ----
        char* q = branch_base;
        auto alloc2 = [&](size_t bytes) -> char* {
            char* r = q;
            q += (bytes + 255) & ~(size_t)255;
            return r;
        };
        float* den1 = (float*)alloc2((size_t)NH * 4);
        float* den2 = (float*)alloc2((size_t)NH * 4);
        float* den3 = (float*)alloc2((size_t)NH * 4);
        float* sc1  = (float*)alloc2((size_t)NH * 4);
        float* sc2  = (float*)alloc2((size_t)NH * 4);
        float* sc3  = (float*)alloc2((size_t)NH * 4);
        hipMemsetAsync(den1, 0, (size_t)(q - (char*)den1), stream);
        int ebl = (E + 63) / 64;
        edge_kernel<<<ebl, 256, 0, stream>>>(edge_h, Wkb, bk, qb, src, dst,
                                             distance, lam,
                                             den1, den2, den3, sc1, sc2, sc3, E);
        combine_kernel<<<(NH + 255) / 256, 256, 0, stream>>>(
            den1, den2, den3, sc1, sc2, sc3, ssum, NH);
    }

    out_kernel<<<nb, 256, 0, stream>>>(v, ssum, Wob, bo, (float*)d_out, N);
}